// Round 18
// baseline (59.067 us; speedup 1.0000x reference)
//
#include <hip/hip_runtime.h>

typedef __attribute__((ext_vector_type(8))) short bf16x8;
typedef __attribute__((ext_vector_type(4))) float f32x4;

#define WT2_BYTES (8ull * 8 * 9 * 8192)           // 4,718,592

static __device__ __forceinline__ ushort f2bf(float f) {
    union { float f; unsigned u; } v; v.f = f;
    unsigned r = v.u + 0x7FFF + ((v.u >> 16) & 1);   // RNE
    return (ushort)(r >> 16);
}
static __device__ __forceinline__ unsigned cvtpk(float a, float b) {
    unsigned r;
    asm("v_cvt_pk_bf16_f32 %0, %1, %2" : "=v"(r) : "v"(a), "v"(b));
    return r;   // lo = bf16(a), hi = bf16(b)
}

// w: (8 dk, 64 o, 64 i, 8 c, 9 f) fp32
// -> wt2: (8 dk, 8 c, 9 f) slices of 8192 B; element (o,i) at byte
//    o*128 + ((i>>3) ^ (o&7))*16 + (i&7)*2   (XOR-swizzle baked in)
__global__ __launch_bounds__(256) void wprep3_kernel(const float* __restrict__ w,
                                                     ushort* __restrict__ wt) {
    __shared__ float raw[4608];
    __shared__ ushort row[72 * 64];
    int bid = blockIdx.x;
    int dk = bid >> 6, o = bid & 63;
    const float* src = w + (size_t)bid * 4608;
    int t = threadIdx.x;
    #pragma unroll
    for (int j = 0; j < 18; ++j) raw[t + 256 * j] = src[t + 256 * j];
    __syncthreads();
    int osw = o & 7;
    #pragma unroll
    for (int p = 0; p < 18; ++p) {
        int idx = t + 256 * p;
        int cf = idx >> 6, i = idx & 63;
        int c = cf / 9, f = cf - c * 9;
        row[cf * 64 + ((i >> 3) ^ osw) * 8 + (i & 7)] = f2bf(raw[i * 72 + c * 9 + f]);
    }
    __syncthreads();
    char* wb = (char*)wt + (size_t)dk * 8 * 9 * 8192 + o * 128;
    #pragma unroll
    for (int q = 0; q < 3; ++q) {
        int idx = q * 256 + t;
        if (idx < 576) {
            int cf = idx >> 3, cc = idx & 7;
            *(uint4*)(wb + (size_t)cf * 8192 + cc * 16) = *(const uint4*)&row[cf * 64 + cc * 8];
        }
    }
}

// conv18: producer-consumer wave specialization. 320 threads = 4 compute
// waves (conv12's barrier-free tap loop: 64l x 32o each, W in regs nf=2) +
// 1 producer wave (stages next tile's X into the alternate XL buffer; its
// staging registers are PRIVATE to it -> no compute-wave spill possible).
// Sync: LDS flags, workgroup acquire/release atomics, s_sleep spin. One
// s_barrier total (prologue). Persistent: grid 704, 3 tiles/block (2112).
__global__ __launch_bounds__(320, 4) void conv18_kernel(
    const float* __restrict__ x, const ushort* __restrict__ wt,
    const float* __restrict__ bias, float* __restrict__ out)
{
    __shared__ __align__(16) ushort XL[2][136 * 64];   // 2 x 17408 B
    __shared__ int flg[4];   // [0..1]=xready[buf], [2..3]=xfree[buf]

    const int GS = 704;
    int t = threadIdx.x, lane = t & 63, wv = t >> 6;
    int ln16 = lane & 15, g = lane >> 4;

    auto dec = [&](int tid, int& bdk, int& dk, int& c, int& V, int& R0) {
        bdk = tid / 33; int tile = tid - bdk * 33;
        dk = bdk & 7;
        int lt;
        if (tile < 28) { c = tile >> 2; lt = tile & 3; } else { c = 7; lt = tile - 28; }
        int lb = lt << 7;
        V = ((c == 7) ? 561 : 505) - lb; if (V > 128) V = 128;
        R0 = 505 * c + lb;
    };

    // staging: virtual thread tt in [0,256) covers rows 0..127 (vector path)
    auto stage_part = [&](int tt, int bdkX, int R0X, ushort* dst) {
        int lq = tt & 31, ig = tt >> 5;
        const float* xb = x + (size_t)bdkX * 64 * 4096;
        float4 v[8];
        bool edge = (R0X < 4) || (R0X > 3964);
        if (!edge) {
            const float* xp = xb + (size_t)ig * 8 * 4096 + (R0X - 4 + lq * 4);
            #pragma unroll
            for (int j = 0; j < 8; ++j) v[j] = *(const float4*)(xp + (size_t)j * 4096);
        } else {
            #pragma unroll
            for (int j = 0; j < 8; ++j) {
                float* pv = (float*)&v[j];
                #pragma unroll
                for (int k = 0; k < 4; ++k) {
                    int xr = R0X - 4 + lq * 4 + k;
                    bool ok = (xr >= 0) && (xr < 4096);
                    int xc = ok ? xr : 0;
                    pv[k] = ok ? xb[(size_t)(ig * 8 + j) * 4096 + xc] : 0.0f;
                }
            }
        }
        #pragma unroll
        for (int k = 0; k < 4; ++k) {
            int r = lq * 4 + k;
            uint4 A;
            A.x = cvtpk(((const float*)&v[0])[k], ((const float*)&v[1])[k]);
            A.y = cvtpk(((const float*)&v[2])[k], ((const float*)&v[3])[k]);
            A.z = cvtpk(((const float*)&v[4])[k], ((const float*)&v[5])[k]);
            A.w = cvtpk(((const float*)&v[6])[k], ((const float*)&v[7])[k]);
            *(uint4*)((char*)dst + r * 128 + ((ig ^ (r & 7)) * 16)) = A;
        }
    };
    auto stage_halo = [&](int tt, int bdkX, int R0X, ushort* dst) {   // tt in [0,64)
        int rh = 128 + (tt >> 3), igh = tt & 7;
        int xr = R0X - 4 + rh;                    // >= 124 always
        bool okh = xr < 4096;
        int xc = okh ? xr : 0;
        const float* xh = x + (size_t)bdkX * 64 * 4096 + (size_t)igh * 8 * 4096 + xc;
        float hv[8];
        #pragma unroll
        for (int j = 0; j < 8; ++j) hv[j] = okh ? xh[(size_t)j * 4096] : 0.0f;
        uint4 A;
        A.x = cvtpk(hv[0], hv[1]); A.y = cvtpk(hv[2], hv[3]);
        A.z = cvtpk(hv[4], hv[5]); A.w = cvtpk(hv[6], hv[7]);
        *(uint4*)((char*)dst + rh * 128 + ((igh ^ (rh & 7)) * 16)) = A;
    };

    int tid0 = blockIdx.x;
    int bdk0, dk0, c0, V0, R00;
    dec(tid0, bdk0, dk0, c0, V0, R00);

    if (t < 4) flg[t] = 0;
    if (t < 256) stage_part(t, bdk0, R00, XL[0]);
    if (t < 64)  stage_halo(t, bdk0, R00, XL[0]);
    __syncthreads();                              // the ONLY barrier

    if (wv < 4) {
        // ================= compute waves =================
        int wr = wv >> 1, wc = wv & 1;
        int Lw = wr << 6, Ow = wc << 5;           // 64l x 32o per wave
        int wo[2][2];
        #pragma unroll
        for (int s = 0; s < 2; ++s)
            #pragma unroll
            for (int nf = 0; nf < 2; ++nf)
                wo[s][nf] = (Ow + nf * 16 + ln16) * 128 + (((s * 4 + g) ^ (ln16 & 7)) * 16);

        int tid = tid0, bdk = bdk0, dk = dk0, c = c0, V = V0, R0 = R00;
        #pragma unroll 1
        for (int k = 0; k < 3; ++k) {
            int p = k & 1;
            if (k > 0) {
                int tgt = (k + 1) >> 1;           // buf1: tile1 -> 1; buf0: tile2 -> 1
                while (__hip_atomic_load(&flg[p], __ATOMIC_ACQUIRE, __HIP_MEMORY_SCOPE_WORKGROUP) < tgt)
                    __builtin_amdgcn_s_sleep(8);
            }
            const char* wsl = (const char*)wt + (size_t)(dk * 8 + c) * 9 * 8192;
            const char* xc_ = (const char*)XL[p];

            bf16x8 w0[2][2], w1[2][2];
            auto loadW = [&](bf16x8 (&d)[2][2], int f) {
                const char* bp = wsl + (size_t)f * 8192;
                #pragma unroll
                for (int s = 0; s < 2; ++s)
                    #pragma unroll
                    for (int nf = 0; nf < 2; ++nf)
                        d[s][nf] = *(const bf16x8*)(bp + wo[s][nf]);
            };
            f32x4 acc[4][2];
            #pragma unroll
            for (int a0 = 0; a0 < 4; ++a0)
                #pragma unroll
                for (int a1 = 0; a1 < 2; ++a1) acc[a0][a1] = (f32x4){0.f, 0.f, 0.f, 0.f};

            auto tap = [&](int f, bf16x8 (&wf)[2][2]) {
                int rbase = Lw + ln16 + f;
                int swz = rbase & 7;
                #pragma unroll
                for (int s = 0; s < 2; ++s) {
                    int cof = ((s * 4 + g) ^ swz) * 16;
                    bf16x8 av[4];
                    #pragma unroll
                    for (int mf = 0; mf < 4; ++mf)
                        av[mf] = *(const bf16x8*)(xc_ + (rbase + mf * 16) * 128 + cof);
                    __builtin_amdgcn_s_setprio(1);
                    #pragma unroll
                    for (int mf = 0; mf < 4; ++mf)
                        #pragma unroll
                        for (int nf = 0; nf < 2; ++nf)
                            acc[mf][nf] = __builtin_amdgcn_mfma_f32_16x16x32_bf16(av[mf], wf[s][nf], acc[mf][nf], 0, 0, 0);
                    __builtin_amdgcn_s_setprio(0);
                }
            };
            loadW(w0, 0); loadW(w1, 1);
            tap(0, w0); loadW(w0, 2);
            tap(1, w1); loadW(w1, 3);
            tap(2, w0); loadW(w0, 4);
            tap(3, w1); loadW(w1, 5);
            tap(4, w0); loadW(w0, 6);
            tap(5, w1); loadW(w1, 7);
            tap(6, w0); loadW(w0, 8);
            tap(7, w1);
            tap(8, w0);

            asm volatile("s_waitcnt lgkmcnt(0)" ::: "memory");   // XL reads landed
            if (lane == 0)
                __hip_atomic_fetch_add(&flg[2 + p], 1, __ATOMIC_RELEASE, __HIP_MEMORY_SCOPE_WORKGROUP);

            float* ob = out + ((size_t)(bdk * 64)) * 4096 + R0;
            #pragma unroll
            for (int nf = 0; nf < 2; ++nf) {
                int o = Ow + nf * 16 + ln16;
                float bvs = bias[(dk * 64 + o) * 8 + c];
                #pragma unroll
                for (int mf = 0; mf < 4; ++mf) {
                    int l = Lw + mf * 16 + g * 4;
                    f32x4 vv = acc[mf][nf];
                    vv[0] += bvs; vv[1] += bvs; vv[2] += bvs; vv[3] += bvs;
                    if (l + 4 <= V) {
                        *(f32x4*)(ob + (size_t)o * 4096 + l) = vv;
                    } else if (l < V) {
                        #pragma unroll
                        for (int r = 0; r < 4; ++r)
                            if (l + r < V) ob[(size_t)o * 4096 + l + r] = vv[r];
                    }
                }
            }
            if (k < 2) { tid += GS; dec(tid, bdk, dk, c, V, R0); }
        }
    } else {
        // ================= producer wave (64 threads) =================
        #pragma unroll 1
        for (int j = 1; j < 3; ++j) {
            int p = j & 1;
            int tgt = 4 * (j >> 1);               // j=1: 0 (fresh buf); j=2: 4
            while (__hip_atomic_load(&flg[2 + p], __ATOMIC_ACQUIRE, __HIP_MEMORY_SCOPE_WORKGROUP) < tgt)
                __builtin_amdgcn_s_sleep(8);
            int bdkJ, dkJ, cJ, VJ, R0J;
            dec(tid0 + j * GS, bdkJ, dkJ, cJ, VJ, R0J);
            #pragma unroll 1
            for (int h = 0; h < 4; ++h)           // rolled: v[8] reused, no spill
                stage_part(lane + 64 * h, bdkJ, R0J, XL[p]);
            stage_halo(lane, bdkJ, R0J, XL[p]);
            asm volatile("s_waitcnt lgkmcnt(0)" ::: "memory");   // data in LDS
            if (lane == 0)
                __hip_atomic_fetch_add(&flg[p], 1, __ATOMIC_RELEASE, __HIP_MEMORY_SCOPE_WORKGROUP);
        }
    }
}

extern "C" void kernel_launch(void* const* d_in, const int* in_sizes, int n_in,
                              void* d_out, int out_size, void* d_ws, size_t ws_size,
                              hipStream_t stream) {
    const float* x    = (const float*)d_in[0];
    const float* wgt  = (const float*)d_in[1];
    const float* bias = (const float*)d_in[2];
    float* out        = (float*)d_out;
    ushort* wt2       = (ushort*)d_ws;            // 4,718,592 B

    hipLaunchKernelGGL(wprep3_kernel, dim3(512), dim3(256), 0, stream, wgt, wt2);
    hipLaunchKernelGGL(conv18_kernel, dim3(704), dim3(320), 0, stream, x, wt2, bias, out);
}

// Round 19
// 49.336 us; speedup vs baseline: 1.1972x; 1.1972x over previous
//
#include <hip/hip_runtime.h>

typedef __attribute__((ext_vector_type(8))) short bf16x8;
typedef __attribute__((ext_vector_type(4))) float f32x4;

#define WT2_BYTES (8ull * 8 * 9 * 8192)           // 4,718,592

static __device__ __forceinline__ ushort f2bf(float f) {
    union { float f; unsigned u; } v; v.f = f;
    unsigned r = v.u + 0x7FFF + ((v.u >> 16) & 1);   // RNE
    return (ushort)(r >> 16);
}
static __device__ __forceinline__ unsigned cvtpk(float a, float b) {
    unsigned r;
    asm("v_cvt_pk_bf16_f32 %0, %1, %2" : "=v"(r) : "v"(a), "v"(b));
    return r;   // lo = bf16(a), hi = bf16(b)
}

// w: (8 dk, 64 o, 64 i, 8 c, 9 f) fp32
// -> wt2: (8 dk, 8 c, 9 f) slices of 8192 B; element (o,i) at byte
//    o*128 + ((i>>3) ^ (o&7))*16 + (i&7)*2   (XOR-swizzle baked in)
__global__ __launch_bounds__(256) void wprep3_kernel(const float* __restrict__ w,
                                                     ushort* __restrict__ wt) {
    __shared__ float raw[4608];          // [i][c*9+f]
    __shared__ ushort row[72 * 64];      // [c*9+f][swizzled 64 i]
    int bid = blockIdx.x;                // dk*64 + o
    int dk = bid >> 6, o = bid & 63;
    const float* src = w + (size_t)bid * 4608;
    int t = threadIdx.x;
    #pragma unroll
    for (int j = 0; j < 18; ++j) raw[t + 256 * j] = src[t + 256 * j];
    __syncthreads();
    int osw = o & 7;
    #pragma unroll
    for (int p = 0; p < 18; ++p) {
        int idx = t + 256 * p;           // (cf, i)
        int cf = idx >> 6, i = idx & 63;
        int c = cf / 9, f = cf - c * 9;
        row[cf * 64 + ((i >> 3) ^ osw) * 8 + (i & 7)] = f2bf(raw[i * 72 + c * 9 + f]);
    }
    __syncthreads();
    char* wb = (char*)wt + (size_t)dk * 8 * 9 * 8192 + o * 128;
    #pragma unroll
    for (int q = 0; q < 3; ++q) {
        int idx = q * 256 + t;           // (cf, cc)
        if (idx < 576) {
            int cf = idx >> 3, cc = idx & 7;
            *(uint4*)(wb + (size_t)cf * 8192 + cc * 16) = *(const uint4*)&row[cf * 64 + cc * 8];
        }
    }
}

// conv12 (measured best, 49.7 us total): 256l x 64o tile, 512 thr, 8 waves
// of 64l x 32o, acc=32 AGPR. W fragments in REGISTERS (4 dwordx4/tap/wave,
// double-buffered) -> zero in-loop barriers; waves drift across taps.
// X: fused fp32->bf16 register transpose into XOR-swizzled LDS (one barrier).
// Epilogue: bias + direct f32x4 stores (4 lanes = 64 B contiguous).
__global__ __launch_bounds__(512, 4) void conv12_kernel(
    const float* __restrict__ x, const ushort* __restrict__ wt,
    const float* __restrict__ bias, float* __restrict__ out)
{
    __shared__ __align__(16) ushort XL[264 * 64];   // 33792 B, [r][i] swizzled

    int bid = blockIdx.x;
    int b = bid / 136, rem = bid - b * 136;   // stride 136 ≡ 0 mod 8: b-sharers same XCD
    int dk = rem / 17, tile = rem - dk * 17;
    int c, lt;
    if (tile < 14) { c = tile >> 1; lt = tile & 1; } else { c = 7; lt = tile - 14; }
    int Sc = 505 * c, lb = lt << 8;
    int V = ((c == 7) ? 561 : 505) - lb; if (V > 256) V = 256;
    int bdk = b * 8 + dk;
    int R0 = Sc + lb;                             // padded row of local row 0

    int t = threadIdx.x, lane = t & 63, wv = t >> 6;
    int ln16 = lane & 15, g = lane >> 4;
    int wr = wv >> 1, wc = wv & 1;
    int Lw = wr << 6, Ow = wc << 5;               // 64l x 32o per wave

    // ---- issue X loads FIRST (one burst, 8 independent float4/thread) ----
    int lq = t & 63, ig = t >> 6;                 // lq: l-quad 0..63, ig: i-group 0..7
    const float* xb = x + (size_t)bdk * 64 * 4096;
    float4 v[8];
    bool edge = (R0 < 4) || (R0 > 3836);          // rows R0-4 .. R0+259 in range?
    if (!edge) {
        const float* xp = xb + (size_t)ig * 8 * 4096 + (R0 - 4 + lq * 4);
        #pragma unroll
        for (int j = 0; j < 8; ++j)
            v[j] = *(const float4*)(xp + (size_t)j * 4096);
    } else {
        #pragma unroll
        for (int j = 0; j < 8; ++j) {
            float* pv = (float*)&v[j];
            #pragma unroll
            for (int k = 0; k < 4; ++k) {
                int xr = R0 - 4 + lq * 4 + k;
                bool ok = (xr >= 0) && (xr < 4096);
                int xc = ok ? xr : 0;
                pv[k] = ok ? xb[(size_t)(ig * 8 + j) * 4096 + xc] : 0.0f;
            }
        }
    }
    // halo rows 256..263: threads t<64, 8 scalar loads each
    float hv[8]; int rh = 0, igh = 0;
    if (t < 64) {
        rh = 256 + (t >> 3);
        igh = t & 7;
        int xr = R0 - 4 + rh;                     // >= 252 always
        bool okh = xr < 4096;
        int xc = okh ? xr : 0;
        const float* xh = xb + (size_t)igh * 8 * 4096 + xc;
        #pragma unroll
        for (int j = 0; j < 8; ++j) hv[j] = okh ? xh[(size_t)j * 4096] : 0.0f;
    }

    // ---- per-lane W fragment addressing into the swizzled wt2 image ----
    const char* wsl = (const char*)wt + (size_t)(dk * 8 + c) * 9 * 8192;
    int wo[2][2];
    #pragma unroll
    for (int s = 0; s < 2; ++s)
        #pragma unroll
        for (int nf = 0; nf < 2; ++nf)
            wo[s][nf] = (Ow + nf * 16 + ln16) * 128 + (((s * 4 + g) ^ (ln16 & 7)) * 16);

    bf16x8 w0[2][2], w1[2][2];
    auto loadW = [&](bf16x8 (&d)[2][2], int f) {
        const char* bp = wsl + (size_t)f * 8192;
        #pragma unroll
        for (int s = 0; s < 2; ++s)
            #pragma unroll
            for (int nf = 0; nf < 2; ++nf)
                d[s][nf] = *(const bf16x8*)(bp + wo[s][nf]);
    };
    loadW(w0, 0);                                 // in flight during cvt/write

    // ---- consume X: register transpose -> swizzled b128 writes ----
    #pragma unroll
    for (int k = 0; k < 4; ++k) {                 // k: l within quad (compile-time)
        int r = lq * 4 + k;
        uint4 A;
        A.x = cvtpk(((const float*)&v[0])[k], ((const float*)&v[1])[k]);
        A.y = cvtpk(((const float*)&v[2])[k], ((const float*)&v[3])[k]);
        A.z = cvtpk(((const float*)&v[4])[k], ((const float*)&v[5])[k]);
        A.w = cvtpk(((const float*)&v[6])[k], ((const float*)&v[7])[k]);
        *(uint4*)((char*)XL + r * 128 + ((ig ^ (r & 7)) * 16)) = A;
    }
    if (t < 64) {
        uint4 A;
        A.x = cvtpk(hv[0], hv[1]); A.y = cvtpk(hv[2], hv[3]);
        A.z = cvtpk(hv[4], hv[5]); A.w = cvtpk(hv[6], hv[7]);
        *(uint4*)((char*)XL + rh * 128 + ((igh ^ (rh & 7)) * 16)) = A;
    }
    loadW(w1, 1);

    asm volatile("s_waitcnt lgkmcnt(0)" ::: "memory");
    __syncthreads();                              // the ONLY barrier

    f32x4 acc[4][2];
    #pragma unroll
    for (int a0 = 0; a0 < 4; ++a0)
        #pragma unroll
        for (int a1 = 0; a1 < 2; ++a1) acc[a0][a1] = (f32x4){0.f, 0.f, 0.f, 0.f};

    auto tap = [&](int f, bf16x8 (&wf)[2][2]) {
        int rbase = Lw + ln16 + f;
        int swz = rbase & 7;                      // +mf*16 doesn't change &7
        #pragma unroll
        for (int s = 0; s < 2; ++s) {
            int cof = ((s * 4 + g) ^ swz) * 16;
            bf16x8 av[4];
            #pragma unroll
            for (int mf = 0; mf < 4; ++mf)
                av[mf] = *(const bf16x8*)((const char*)XL + (rbase + mf * 16) * 128 + cof);
            __builtin_amdgcn_s_setprio(1);
            #pragma unroll
            for (int mf = 0; mf < 4; ++mf)
                #pragma unroll
                for (int nf = 0; nf < 2; ++nf)
                    acc[mf][nf] = __builtin_amdgcn_mfma_f32_16x16x32_bf16(av[mf], wf[s][nf], acc[mf][nf], 0, 0, 0);
            __builtin_amdgcn_s_setprio(0);
        }
    };

    tap(0, w0); loadW(w0, 2);
    tap(1, w1); loadW(w1, 3);
    tap(2, w0); loadW(w0, 4);
    tap(3, w1); loadW(w1, 5);
    tap(4, w0); loadW(w0, 6);
    tap(5, w1); loadW(w1, 7);
    tap(6, w0); loadW(w0, 8);
    tap(7, w1);
    tap(8, w0);

    // ---- epilogue: bias + direct f32x4 stores (4 lanes = 64 B contiguous) ----
    float* ob = out + ((size_t)(bdk * 64)) * 4096 + Sc + lb;
    #pragma unroll
    for (int nf = 0; nf < 2; ++nf) {
        int o = Ow + nf * 16 + ln16;
        float bvs = bias[(dk * 64 + o) * 8 + c];
        #pragma unroll
        for (int mf = 0; mf < 4; ++mf) {
            int l = Lw + mf * 16 + g * 4;
            f32x4 vv = acc[mf][nf];
            vv[0] += bvs; vv[1] += bvs; vv[2] += bvs; vv[3] += bvs;
            if (l + 4 <= V) {
                *(f32x4*)(ob + (size_t)o * 4096 + l) = vv;
            } else if (l < V) {
                #pragma unroll
                for (int r = 0; r < 4; ++r)
                    if (l + r < V) ob[(size_t)o * 4096 + l + r] = vv[r];
            }
        }
    }
}

extern "C" void kernel_launch(void* const* d_in, const int* in_sizes, int n_in,
                              void* d_out, int out_size, void* d_ws, size_t ws_size,
                              hipStream_t stream) {
    const float* x    = (const float*)d_in[0];
    const float* wgt  = (const float*)d_in[1];
    const float* bias = (const float*)d_in[2];
    float* out        = (float*)d_out;
    ushort* wt2       = (ushort*)d_ws;            // 4,718,592 B

    hipLaunchKernelGGL(wprep3_kernel, dim3(512), dim3(256), 0, stream, wgt, wt2);
    hipLaunchKernelGGL(conv12_kernel, dim3(1088), dim3(512), 0, stream, x, wt2, bias, out);
}

// Round 21
// 49.309 us; speedup vs baseline: 1.1979x; 1.0005x over previous
//
#include <hip/hip_runtime.h>

typedef __attribute__((ext_vector_type(8))) short bf16x8;
typedef __attribute__((ext_vector_type(4))) float f32x4;

#define WT2_BYTES (8ull * 8 * 9 * 8192)           // 4,718,592

static __device__ __forceinline__ ushort f2bf(float f) {
    union { float f; unsigned u; } v; v.f = f;
    unsigned r = v.u + 0x7FFF + ((v.u >> 16) & 1);   // RNE
    return (ushort)(r >> 16);
}
static __device__ __forceinline__ unsigned cvtpk(float a, float b) {
    unsigned r;
    asm("v_cvt_pk_bf16_f32 %0, %1, %2" : "=v"(r) : "v"(a), "v"(b));
    return r;   // lo = bf16(a), hi = bf16(b)
}

// w: (8 dk, 64 o, 64 i, 8 c, 9 f) fp32
// -> wt2: (8 dk, 8 c, 9 f) slices of 8192 B; element (o,i) at byte
//    o*128 + ((i>>3) ^ (o&7))*16 + (i&7)*2   (XOR-swizzle baked in)
__global__ __launch_bounds__(256) void wprep3_kernel(const float* __restrict__ w,
                                                     ushort* __restrict__ wt) {
    __shared__ float raw[4608];          // [i][c*9+f]
    __shared__ ushort row[72 * 64];      // [c*9+f][swizzled 64 i]
    int bid = blockIdx.x;                // dk*64 + o
    int dk = bid >> 6, o = bid & 63;
    const float* src = w + (size_t)bid * 4608;
    int t = threadIdx.x;
    #pragma unroll
    for (int j = 0; j < 18; ++j) raw[t + 256 * j] = src[t + 256 * j];
    __syncthreads();
    int osw = o & 7;
    #pragma unroll
    for (int p = 0; p < 18; ++p) {
        int idx = t + 256 * p;           // (cf, i)
        int cf = idx >> 6, i = idx & 63;
        int c = cf / 9, f = cf - c * 9;
        row[cf * 64 + ((i >> 3) ^ osw) * 8 + (i & 7)] = f2bf(raw[i * 72 + c * 9 + f]);
    }
    __syncthreads();
    char* wb = (char*)wt + (size_t)dk * 8 * 9 * 8192 + o * 128;
    #pragma unroll
    for (int q = 0; q < 3; ++q) {
        int idx = q * 256 + t;           // (cf, cc)
        if (idx < 576) {
            int cf = idx >> 3, cc = idx & 7;
            *(uint4*)(wb + (size_t)cf * 8192 + cc * 16) = *(const uint4*)&row[cf * 64 + cc * 8];
        }
    }
}

// conv12 (measured best, 49.3 us total): 256l x 64o tile, 512 thr, 8 waves
// of 64l x 32o, acc=32 AGPR. W fragments in REGISTERS (4 dwordx4/tap/wave,
// double-buffered) -> zero in-loop barriers; waves drift across taps.
// X: fused fp32->bf16 register transpose into XOR-swizzled LDS (one barrier).
// Epilogue: bias + direct f32x4 stores (4 lanes = 64 B contiguous).
__global__ __launch_bounds__(512, 4) void conv12_kernel(
    const float* __restrict__ x, const ushort* __restrict__ wt,
    const float* __restrict__ bias, float* __restrict__ out)
{
    __shared__ __align__(16) ushort XL[264 * 64];   // 33792 B, [r][i] swizzled

    int bid = blockIdx.x;
    int b = bid / 136, rem = bid - b * 136;   // stride 136 ≡ 0 mod 8: b-sharers same XCD
    int dk = rem / 17, tile = rem - dk * 17;
    int c, lt;
    if (tile < 14) { c = tile >> 1; lt = tile & 1; } else { c = 7; lt = tile - 14; }
    int Sc = 505 * c, lb = lt << 8;
    int V = ((c == 7) ? 561 : 505) - lb; if (V > 256) V = 256;
    int bdk = b * 8 + dk;
    int R0 = Sc + lb;                             // padded row of local row 0

    int t = threadIdx.x, lane = t & 63, wv = t >> 6;
    int ln16 = lane & 15, g = lane >> 4;
    int wr = wv >> 1, wc = wv & 1;
    int Lw = wr << 6, Ow = wc << 5;               // 64l x 32o per wave

    // ---- issue X loads FIRST (one burst, 8 independent float4/thread) ----
    int lq = t & 63, ig = t >> 6;                 // lq: l-quad 0..63, ig: i-group 0..7
    const float* xb = x + (size_t)bdk * 64 * 4096;
    float4 v[8];
    bool edge = (R0 < 4) || (R0 > 3836);          // rows R0-4 .. R0+259 in range?
    if (!edge) {
        const float* xp = xb + (size_t)ig * 8 * 4096 + (R0 - 4 + lq * 4);
        #pragma unroll
        for (int j = 0; j < 8; ++j)
            v[j] = *(const float4*)(xp + (size_t)j * 4096);
    } else {
        #pragma unroll
        for (int j = 0; j < 8; ++j) {
            float* pv = (float*)&v[j];
            #pragma unroll
            for (int k = 0; k < 4; ++k) {
                int xr = R0 - 4 + lq * 4 + k;
                bool ok = (xr >= 0) && (xr < 4096);
                int xc = ok ? xr : 0;
                pv[k] = ok ? xb[(size_t)(ig * 8 + j) * 4096 + xc] : 0.0f;
            }
        }
    }
    // halo rows 256..263: threads t<64, 8 scalar loads each
    float hv[8]; int rh = 0, igh = 0;
    if (t < 64) {
        rh = 256 + (t >> 3);
        igh = t & 7;
        int xr = R0 - 4 + rh;                     // >= 252 always
        bool okh = xr < 4096;
        int xc = okh ? xr : 0;
        const float* xh = xb + (size_t)igh * 8 * 4096 + xc;
        #pragma unroll
        for (int j = 0; j < 8; ++j) hv[j] = okh ? xh[(size_t)j * 4096] : 0.0f;
    }

    // ---- per-lane W fragment addressing into the swizzled wt2 image ----
    const char* wsl = (const char*)wt + (size_t)(dk * 8 + c) * 9 * 8192;
    int wo[2][2];
    #pragma unroll
    for (int s = 0; s < 2; ++s)
        #pragma unroll
        for (int nf = 0; nf < 2; ++nf)
            wo[s][nf] = (Ow + nf * 16 + ln16) * 128 + (((s * 4 + g) ^ (ln16 & 7)) * 16);

    bf16x8 w0[2][2], w1[2][2];
    auto loadW = [&](bf16x8 (&d)[2][2], int f) {
        const char* bp = wsl + (size_t)f * 8192;
        #pragma unroll
        for (int s = 0; s < 2; ++s)
            #pragma unroll
            for (int nf = 0; nf < 2; ++nf)
                d[s][nf] = *(const bf16x8*)(bp + wo[s][nf]);
    };
    loadW(w0, 0);                                 // in flight during cvt/write

    // ---- consume X: register transpose -> swizzled b128 writes ----
    #pragma unroll
    for (int k = 0; k < 4; ++k) {                 // k: l within quad (compile-time)
        int r = lq * 4 + k;
        uint4 A;
        A.x = cvtpk(((const float*)&v[0])[k], ((const float*)&v[1])[k]);
        A.y = cvtpk(((const float*)&v[2])[k], ((const float*)&v[3])[k]);
        A.z = cvtpk(((const float*)&v[4])[k], ((const float*)&v[5])[k]);
        A.w = cvtpk(((const float*)&v[6])[k], ((const float*)&v[7])[k]);
        *(uint4*)((char*)XL + r * 128 + ((ig ^ (r & 7)) * 16)) = A;
    }
    if (t < 64) {
        uint4 A;
        A.x = cvtpk(hv[0], hv[1]); A.y = cvtpk(hv[2], hv[3]);
        A.z = cvtpk(hv[4], hv[5]); A.w = cvtpk(hv[6], hv[7]);
        *(uint4*)((char*)XL + rh * 128 + ((igh ^ (rh & 7)) * 16)) = A;
    }
    loadW(w1, 1);

    asm volatile("s_waitcnt lgkmcnt(0)" ::: "memory");
    __syncthreads();                              // the ONLY barrier

    f32x4 acc[4][2];
    #pragma unroll
    for (int a0 = 0; a0 < 4; ++a0)
        #pragma unroll
        for (int a1 = 0; a1 < 2; ++a1) acc[a0][a1] = (f32x4){0.f, 0.f, 0.f, 0.f};

    auto tap = [&](int f, bf16x8 (&wf)[2][2]) {
        int rbase = Lw + ln16 + f;
        int swz = rbase & 7;                      // +mf*16 doesn't change &7
        #pragma unroll
        for (int s = 0; s < 2; ++s) {
            int cof = ((s * 4 + g) ^ swz) * 16;
            bf16x8 av[4];
            #pragma unroll
            for (int mf = 0; mf < 4; ++mf)
                av[mf] = *(const bf16x8*)((const char*)XL + (rbase + mf * 16) * 128 + cof);
            __builtin_amdgcn_s_setprio(1);
            #pragma unroll
            for (int mf = 0; mf < 4; ++mf)
                #pragma unroll
                for (int nf = 0; nf < 2; ++nf)
                    acc[mf][nf] = __builtin_amdgcn_mfma_f32_16x16x32_bf16(av[mf], wf[s][nf], acc[mf][nf], 0, 0, 0);
            __builtin_amdgcn_s_setprio(0);
        }
    };

    tap(0, w0); loadW(w0, 2);
    tap(1, w1); loadW(w1, 3);
    tap(2, w0); loadW(w0, 4);
    tap(3, w1); loadW(w1, 5);
    tap(4, w0); loadW(w0, 6);
    tap(5, w1); loadW(w1, 7);
    tap(6, w0); loadW(w0, 8);
    tap(7, w1);
    tap(8, w0);

    // ---- epilogue: bias + direct f32x4 stores (4 lanes = 64 B contiguous) ----
    float* ob = out + ((size_t)(bdk * 64)) * 4096 + Sc + lb;
    #pragma unroll
    for (int nf = 0; nf < 2; ++nf) {
        int o = Ow + nf * 16 + ln16;
        float bvs = bias[(dk * 64 + o) * 8 + c];
        #pragma unroll
        for (int mf = 0; mf < 4; ++mf) {
            int l = Lw + mf * 16 + g * 4;
            f32x4 vv = acc[mf][nf];
            vv[0] += bvs; vv[1] += bvs; vv[2] += bvs; vv[3] += bvs;
            if (l + 4 <= V) {
                *(f32x4*)(ob + (size_t)o * 4096 + l) = vv;
            } else if (l < V) {
                #pragma unroll
                for (int r = 0; r < 4; ++r)
                    if (l + r < V) ob[(size_t)o * 4096 + l + r] = vv[r];
            }
        }
    }
}

extern "C" void kernel_launch(void* const* d_in, const int* in_sizes, int n_in,
                              void* d_out, int out_size, void* d_ws, size_t ws_size,
                              hipStream_t stream) {
    const float* x    = (const float*)d_in[0];
    const float* wgt  = (const float*)d_in[1];
    const float* bias = (const float*)d_in[2];
    float* out        = (float*)d_out;
    ushort* wt2       = (ushort*)d_ws;            // 4,718,592 B

    hipLaunchKernelGGL(wprep3_kernel, dim3(512), dim3(256), 0, stream, wgt, wt2);
    hipLaunchKernelGGL(conv12_kernel, dim3(1088), dim3(512), 0, stream, x, wt2, bias, out);
}